// Round 9
// baseline (351.133 us; speedup 1.0000x reference)
//
#include <hip/hip_runtime.h>
#include <math.h>

#define THREADS 256
#define SORTT 1024
#define NMST 256

// ---------------- problem constants (fixed by reference setup) ----------------
constexpr int NLEV  = 5;
constexpr int NB    = 16;     // batch
constexpr int NC    = 80;     // classes (label = c+1)
constexpr int TOPN  = 300;
constexpr int KC    = NLEV * TOPN;   // 1500 candidates per image
constexpr int KROWS = 1536;          // padded rows for NMS bitmask
constexpr int WORDS = 24;            // 1536 / 64
constexpr int POSTN = 100;
constexpr int CAP   = 4096;          // per-(b,level) candidate pool
constexpr int NBINS = 2048;          // score-histogram bins over [0.25, 1.0)
constexpr int NPAIR = NLEV * NB;     // 80

constexpr int HW0 = 12800, HW1 = 3200, HW2 = 800, HW3 = 208, HW4 = 56;
constexpr int CH0 = 63, CH1 = 16, CH2 = 4, CH3 = 2, CH4 = 1;  // 16384-elem chunks per (b,level)
constexpr int CHUNKS = CH0 + CH1 + CH2 + CH3 + CH4;           // 86
constexpr int CHUNK_ELEMS = 16384;

// sigmoid(ctr) precompute: per-level bases into sct[] (floats), layout [li][b][hw]
constexpr int SCTB0 = 0;
constexpr int SCTB1 = 204800;
constexpr int SCTB2 = 256000;
constexpr int SCTB3 = 268800;
constexpr int SCTB4 = 272128;
constexpr int SCTN  = 273024;

// group-max skip list: 256-element groups, layout [li][b][g] (u16)
constexpr int GPL0 = 4000, GPL1 = 1000, GPL2 = 250, GPL3 = 65, GPL4 = 18;
constexpr int GMXB0 = 0;
constexpr int GMXB1 = GMXB0 + NB * GPL0;
constexpr int GMXB2 = GMXB1 + NB * GPL1;
constexpr int GMXB3 = GMXB2 + NB * GPL2;
constexpr int GMXB4 = GMXB3 + NB * GPL3;
constexpr int GMXN  = GMXB4 + NB * GPL4;

// ---------------- workspace layout ----------------
constexpr size_t align256(size_t x) { return (x + 255) & ~(size_t)255; }
constexpr size_t OFF_HIST = 0;
constexpr size_t OFF_CNT  = OFF_HIST + (size_t)NPAIR * NBINS * 4;
constexpr size_t OFF_CAND = align256(OFF_CNT + (size_t)NPAIR * 4);
constexpr size_t OFF_CBOX = align256(OFF_CAND + (size_t)NPAIR * CAP * 8);
constexpr size_t OFF_CSC  = align256(OFF_CBOX + (size_t)NB * KC * 4 * 4);
constexpr size_t OFF_CLB  = align256(OFF_CSC  + (size_t)NB * KC * 4);
constexpr size_t OFF_SSC  = align256(OFF_CLB  + (size_t)NB * KC * 4);
constexpr size_t OFF_SLB  = align256(OFF_SSC  + (size_t)NB * KC * 4);
constexpr size_t OFF_SBOX = align256(OFF_SLB  + (size_t)NB * KC * 4);
constexpr size_t OFF_OBOX = align256(OFF_SBOX + (size_t)NB * KC * 4 * 4);
constexpr size_t OFF_M    = align256(OFF_OBOX + (size_t)NB * KC * 4 * 4);
constexpr size_t OFF_SCT  = align256(OFF_M + (size_t)NB * KROWS * WORDS * 8);
constexpr size_t OFF_GMX  = align256(OFF_SCT + (size_t)SCTN * 4);
// total ~15.8 MB

struct Cand { float s; int i; };

// ---------------- helpers ----------------
__device__ __forceinline__ float sigm(float x) { return 1.0f / (1.0f + expf(-x)); }

// fast sigmoid (hw v_exp_f32 + v_rcp_f32, <=~4 ulp). Used ONLY for the histogram /
// skip-list (threshold selection): |approx key - exact key| <= 1 bin, compensated
// by collecting key >= TA-1 and gating groups by gmx+1 >= Tv. Collect/select use
// the exact sigm() so the final output is bit-identical.
__device__ __forceinline__ float sigf(float x) {
#if __has_builtin(__builtin_amdgcn_exp2f) && __has_builtin(__builtin_amdgcn_rcpf)
    float e = __builtin_amdgcn_exp2f(__fmul_rn(x, -1.44269504088896340736f));
    return __builtin_amdgcn_rcpf(__fadd_rn(1.0f, e));
#else
    return 1.0f / (1.0f + __expf(-x));
#endif
}

// monotone key over score in (0,1): 2048 bins over [0.25,1.0), everything below -> bin 0
__device__ __forceinline__ unsigned scoreKey(float s) {
    unsigned b = __float_as_uint(s);
    unsigned k = (b < 0x3E800000u) ? 0u : ((b - 0x3E800000u) >> 13);
    return (k > 2047u) ? 2047u : k;
}

__device__ __forceinline__ unsigned long long readlane64(unsigned long long v, int l) {
    unsigned lo = (unsigned)__builtin_amdgcn_readlane((int)(unsigned)(v & 0xffffffffull), l);
    unsigned hi = (unsigned)__builtin_amdgcn_readlane((int)(unsigned)(v >> 32), l);
    return ((unsigned long long)hi << 32) | lo;
}

__device__ void bitonicShared(float* ss, int* si, int N) {
    for (int k = 2; k <= N; k <<= 1) {
        for (int j = k >> 1; j > 0; j >>= 1) {
            __syncthreads();
            for (int i = threadIdx.x; i < N; i += blockDim.x) {
                int ixj = i ^ j;
                if (ixj > i) {
                    float s1 = ss[i], s2 = ss[ixj];
                    int a1 = si[i], a2 = si[ixj];
                    bool bef = (s1 > s2) || (s1 == s2 && a1 < a2);   // desc, idx asc
                    bool up = ((i & k) == 0);
                    if (up ? !bef : bef) { ss[i] = s2; ss[ixj] = s1; si[i] = a2; si[ixj] = a1; }
                }
            }
        }
    }
    __syncthreads();
}

// ---------------- K0: fused zero (hist+cnt) + sigmoid(ctr) precompute ----------------
__global__ __launch_bounds__(THREADS) void k_init(
        const float* t0, const float* t1, const float* t2, const float* t3, const float* t4,
        float* __restrict__ sct, unsigned* __restrict__ zp, int zn) {
    int i = blockIdx.x * THREADS + threadIdx.x;
    if (i < zn) zp[i] = 0;
    if (i < SCTN) {
        float x;
        if (i < SCTB1)      x = t0[i - SCTB0];
        else if (i < SCTB2) x = t1[i - SCTB1];
        else if (i < SCTB3) x = t2[i - SCTB2];
        else if (i < SCTB4) x = t3[i - SCTB3];
        else                x = t4[i - SCTB4];
        sct[i] = sigm(x);   // exact: same formula as reference sigmoid usage
    }
}

// ---------------- K1: approx histogram + per-256-group max approx key ----------------
// 512-elem blocks: each lane loads 2x float4 (32B contiguous). All NE and HW are
// divisible by 8, so the two float4s never straddle a class row.
template<int HW, int SCTB, int GPL, int GMXB>
__device__ __forceinline__ void histChunkV(int chunkLocal, int b,
        const float* __restrict__ cls, const float* __restrict__ sct,
        unsigned short* __restrict__ gmx, unsigned* __restrict__ h) {
    constexpr int NE = HW * NC;
    const float* cp = cls + (size_t)b * NE;
    const float* tb = sct + SCTB + b * HW;
    unsigned short* gp = gmx + GMXB + (size_t)b * GPL;
    int w = threadIdx.x >> 6, lane = threadIdx.x & 63;
    int half = lane >> 5, hlane = lane & 31;
    for (int bi = w; bi < 32; bi += 4) {
        int ebase = (chunkLocal * 32 + bi) * 512;
        if (ebase >= NE) break;
        int e = ebase + lane * 8;
        int kmax = 0;
        if (e < NE) {   // NE%8==0 -> e<NE implies e+7<NE
            int c = e / HW; int hwb = e - c * HW;
            float4 xa = *(const float4*)(cp + e);
            float4 xb = *(const float4*)(cp + e + 4);
            float4 ta = *(const float4*)(tb + hwb);
            float4 tc = *(const float4*)(tb + hwb + 4);
            float xs[8] = {xa.x, xa.y, xa.z, xa.w, xb.x, xb.y, xb.z, xb.w};
            float ts[8] = {ta.x, ta.y, ta.z, ta.w, tc.x, tc.y, tc.z, tc.w};
            #pragma unroll
            for (int q = 0; q < 8; ++q) {
                float scls = sigf(xs[q]);                // FAST sigmoid (approx key)
                float s = __fmul_rn(scls, ts[q]);
                unsigned key = scoreKey(s);
                if (key) atomicAdd(&h[key], 1u);
                kmax = max(kmax, (int)key);
            }
        }
        // half-wave (32-lane) max reduce: each half covers one 256-elem group
        #pragma unroll
        for (int sh = 1; sh < 32; sh <<= 1) kmax = max(kmax, __shfl_xor(kmax, sh, 64));
        int g = (ebase >> 8) + half;
        if (hlane == 0 && g * 256 < NE) gp[g] = (unsigned short)kmax;
    }
}

__global__ __launch_bounds__(THREADS) void k_hist(
        const float* c0, const float* c1, const float* c2, const float* c3, const float* c4,
        const float* __restrict__ sct, unsigned short* __restrict__ gmx, unsigned* ghist) {
    __shared__ unsigned h[NBINS];
    for (int k = threadIdx.x; k < NBINS; k += THREADS) h[k] = 0;
    __syncthreads();
    int cx = blockIdx.x, b = blockIdx.y;
    int li;
    if (cx < CH0)                 { histChunkV<HW0,SCTB0,GPL0,GMXB0>(cx, b, c0, sct, gmx, h); li = 0; }
    else if (cx < CH0+CH1)        { histChunkV<HW1,SCTB1,GPL1,GMXB1>(cx-CH0, b, c1, sct, gmx, h); li = 1; }
    else if (cx < CH0+CH1+CH2)    { histChunkV<HW2,SCTB2,GPL2,GMXB2>(cx-CH0-CH1, b, c2, sct, gmx, h); li = 2; }
    else if (cx < CH0+CH1+CH2+CH3){ histChunkV<HW3,SCTB3,GPL3,GMXB3>(cx-CH0-CH1-CH2, b, c3, sct, gmx, h); li = 3; }
    else                          { histChunkV<HW4,SCTB4,GPL4,GMXB4>(cx-CH0-CH1-CH2-CH3, b, c4, sct, gmx, h); li = 4; }
    __syncthreads();
    unsigned* gp = ghist + (size_t)(li * NB + b) * NBINS;
    for (int k = threadIdx.x; k < NBINS; k += THREADS) {
        unsigned v = h[k];
        if (v) atomicAdd(&gp[k], v);
    }
}

// ---------------- K3: skip-list compaction, batched loads; inline threshold ----------------
constexpr int LBUF = 1024;
constexpr int GB = 8;

template<int HW, int SCTB, int GPL, int GMXB>
__device__ __forceinline__ void collectChunkV(int chunkLocal, int b, int li, unsigned Tv,
        const float* __restrict__ cls, const float* __restrict__ sct,
        const unsigned short* __restrict__ gmx,
        Cand* __restrict__ candAll, unsigned* __restrict__ cnt,
        Cand* __restrict__ lbuf, unsigned* __restrict__ lcnt,
        short* __restrict__ glist, int* __restrict__ gcnt) {
    constexpr int NE = HW * NC;
    int pid = li * NB + b;
    Cand* cd = candAll + (size_t)pid * CAP;
    const float* cp = cls + (size_t)b * NE;
    const float* tb = sct + SCTB + b * HW;
    const unsigned short* gp = gmx + GMXB + (size_t)b * GPL;
    // build compact passing-group list
    if (threadIdx.x < 64) {
        int g = chunkLocal * 64 + threadIdx.x;
        bool ok = ((size_t)g * 256 < (size_t)NE);
        if (ok && Tv) ok = ((unsigned)gp[g] + 1u >= Tv);   // gmx is max APPROX key: +1 slack
        unsigned long long m = __ballot(ok);
        int pos = __popcll(m & ((1ull << threadIdx.x) - 1ull));
        if (ok) glist[pos] = (short)g;
        if (threadIdx.x == 0) *gcnt = __popcll(m);
    }
    __syncthreads();
    int n = *gcnt;
    for (int base = 0; base < n; base += GB) {
        float xv[GB], tv[GB];
        int ev[GB];
        bool okv[GB];
        #pragma unroll
        for (int q = 0; q < GB; ++q) {
            int gi = base + q;
            int g = glist[(gi < n) ? gi : 0];
            int e = g * 256 + (int)threadIdx.x;
            bool ok = (gi < n) && (e < NE);
            e = ok ? e : 0;
            int c = e / HW; int hw = e - c * HW;
            xv[q] = cp[e];
            tv[q] = tb[hw];
            ev[q] = e;
            okv[q] = ok;
        }
        __builtin_amdgcn_sched_barrier(0);   // keep the 2*GB loads batched above the uses
        #pragma unroll
        for (int q = 0; q < GB; ++q) {
            float scls = sigm(xv[q]);        // EXACT sigmoid for stored score
            float s = __fmul_rn(scls, tv[q]);
            unsigned key = scoreKey(s);
            bool take = okv[q] && (Tv ? (key >= Tv) : (scls > 0.05f));
            if (take) {
                int e = ev[q];
                int c = e / HW; int hw = e - c * HW;
                unsigned slot = atomicAdd(lcnt, 1u);
                if (slot < (unsigned)LBUF) { lbuf[slot].s = s; lbuf[slot].i = hw * NC + c; }
                else {
                    unsigned gs = atomicAdd(&cnt[pid], 1u);   // rare fallback
                    if (gs < (unsigned)CAP) { cd[gs].s = s; cd[gs].i = hw * NC + c; }
                }
            }
        }
    }
}

__global__ __launch_bounds__(THREADS) void k_collect(
        const float* c0, const float* c1, const float* c2, const float* c3, const float* c4,
        const float* __restrict__ sct, const unsigned short* __restrict__ gmx,
        const unsigned* __restrict__ ghist, Cand* cand, unsigned* cnt) {
    __shared__ Cand lbuf[LBUF];
    __shared__ unsigned lcnt, gbase;
    __shared__ short glist[64];
    __shared__ int gcnt;
    __shared__ unsigned seg[THREADS];
    __shared__ unsigned shTv;
    if (threadIdx.x == 0) lcnt = 0;
    int cx = blockIdx.x, b = blockIdx.y;
    int li, cl;
    if (cx < CH0)                  { li = 0; cl = cx; }
    else if (cx < CH0+CH1)         { li = 1; cl = cx - CH0; }
    else if (cx < CH0+CH1+CH2)     { li = 2; cl = cx - CH0 - CH1; }
    else if (cx < CH0+CH1+CH2+CH3) { li = 3; cl = cx - CH0 - CH1 - CH2; }
    else                           { li = 4; cl = cx - CH0 - CH1 - CH2 - CH3; }
    int pid = li * NB + b;
    // inline threshold (same math as the old k_thresh, recomputed per block)
    {
        const unsigned* h = ghist + (size_t)pid * NBINS;
        constexpr int SB = NBINS / THREADS;   // 8
        unsigned s = 0;
        for (int k = 0; k < SB; ++k) s += h[threadIdx.x * SB + k];
        seg[threadIdx.x] = s;
        __syncthreads();
        if (threadIdx.x == 0) {
            unsigned acc = 0; unsigned TA = 0;
            int t = THREADS - 1;
            for (; t >= 0; --t) {
                if (acc + seg[t] >= (unsigned)TOPN) break;
                acc += seg[t];
            }
            if (t >= 0) {
                int lo = t * SB;
                int bin = lo + SB - 1;
                for (; bin >= lo; --bin) { acc += h[bin]; if (acc >= (unsigned)TOPN) break; }
                TA = (unsigned)max(bin, lo);
            }
            shTv = (TA >= 1) ? (TA - 1) : 0;   // 0 => degenerate fallback (collect scls>0.05)
        }
        __syncthreads();
    }
    unsigned Tv = shTv;
    switch (li) {
        case 0: collectChunkV<HW0,SCTB0,GPL0,GMXB0>(cl, b, 0, Tv, c0, sct, gmx, cand, cnt, lbuf, &lcnt, glist, &gcnt); break;
        case 1: collectChunkV<HW1,SCTB1,GPL1,GMXB1>(cl, b, 1, Tv, c1, sct, gmx, cand, cnt, lbuf, &lcnt, glist, &gcnt); break;
        case 2: collectChunkV<HW2,SCTB2,GPL2,GMXB2>(cl, b, 2, Tv, c2, sct, gmx, cand, cnt, lbuf, &lcnt, glist, &gcnt); break;
        case 3: collectChunkV<HW3,SCTB3,GPL3,GMXB3>(cl, b, 3, Tv, c3, sct, gmx, cand, cnt, lbuf, &lcnt, glist, &gcnt); break;
        default: collectChunkV<HW4,SCTB4,GPL4,GMXB4>(cl, b, 4, Tv, c4, sct, gmx, cand, cnt, lbuf, &lcnt, glist, &gcnt); break;
    }
    __syncthreads();
    unsigned n = lcnt; if (n > (unsigned)LBUF) n = LBUF;
    if (threadIdx.x == 0) gbase = n ? atomicAdd(&cnt[pid], n) : 0u;
    __syncthreads();
    Cand* cd = cand + (size_t)pid * CAP;
    for (unsigned i = threadIdx.x; i < n; i += THREADS) {
        unsigned s = gbase + i;
        if (s < (unsigned)CAP) cd[s] = lbuf[i];
    }
}

// ---------------- K4: exact top-300 per (b,level) + decode ----------------
__global__ __launch_bounds__(THREADS) void k_select(
        const Cand* __restrict__ candAll, const unsigned* __restrict__ cntAll,
        const float* l0, const float* l1, const float* l2, const float* l3, const float* l4,
        const float* b0, const float* b1, const float* b2, const float* b3, const float* b4,
        float* __restrict__ cbox, float* __restrict__ csc, int* __restrict__ clb) {
    __shared__ float ss[CAP];
    __shared__ int si[CAP];
    int pid = blockIdx.x;
    int li = pid / NB, b = pid - li * NB;
    int n = (int)min(cntAll[pid], (unsigned)CAP);
    const Cand* cd = candAll + (size_t)pid * CAP;
    int N = 2; while (N < n) N <<= 1;
    for (int k = threadIdx.x; k < N; k += THREADS) {
        if (k < n) { ss[k] = cd[k].s; si[k] = cd[k].i; }
        else       { ss[k] = -INFINITY; si[k] = 0x40000000 + k; }
    }
    __syncthreads();
    bitonicShared(ss, si, N);

    const float* locp; const float* boxp; int HW;
    switch (li) {
        case 0: locp = l0; boxp = b0; HW = HW0; break;
        case 1: locp = l1; boxp = b1; HW = HW1; break;
        case 2: locp = l2; boxp = b2; HW = HW2; break;
        case 3: locp = l3; boxp = b3; HW = HW3; break;
        default: locp = l4; boxp = b4; HW = HW4; break;
    }
    for (int j = threadIdx.x; j < TOPN; j += THREADS) {
        int cidx = b * KC + li * TOPN + j;
        bool ok = (j < n);
        float s = ok ? ss[j] : -INFINITY;
        ok = ok && (s > 0.0f);
        if (ok) {
            int idx = si[j];
            int hw = idx / NC, c = idx - hw * NC;
            float lx = locp[hw * 2 + 0], ly = locp[hw * 2 + 1];
            const float* bp = boxp + (size_t)b * 4 * HW + hw;
            float bl = bp[0], bt = bp[HW], br = bp[2 * HW], bb = bp[3 * HW];
            float x1 = fminf(fmaxf(__fsub_rn(lx, bl), 0.0f), 1023.0f);
            float y1 = fminf(fmaxf(__fsub_rn(ly, bt), 0.0f),  799.0f);
            float x2 = fminf(fmaxf(__fadd_rn(lx, br), 0.0f), 1023.0f);
            float y2 = fminf(fmaxf(__fadd_rn(ly, bb), 0.0f),  799.0f);
            cbox[cidx * 4 + 0] = x1; cbox[cidx * 4 + 1] = y1;
            cbox[cidx * 4 + 2] = x2; cbox[cidx * 4 + 3] = y2;
            csc[cidx] = sqrtf(fmaxf(s, 1e-12f));
            clb[cidx] = c + 1;
        } else {
            cbox[cidx * 4 + 0] = 0.0f; cbox[cidx * 4 + 1] = 0.0f;
            cbox[cidx * 4 + 2] = 0.0f; cbox[cidx * 4 + 3] = 0.0f;
            csc[cidx] = -INFINITY;
            clb[cidx] = 0;
        }
    }
}

// ---------------- K5a: per-image sort by score desc (1024 threads) ----------------
__global__ __launch_bounds__(SORTT) void k_sortimg(
        const float* __restrict__ csc, const int* __restrict__ clb, const float* __restrict__ cbox,
        float* __restrict__ ssc, int* __restrict__ slb, float* __restrict__ sbox, float* __restrict__ obox) {
    int b = blockIdx.x;
    __shared__ float ss[2048];
    __shared__ int si[2048];
    for (int k = threadIdx.x; k < 2048; k += SORTT) {
        if (k < KC) { ss[k] = csc[b * KC + k]; si[k] = k; }
        else        { ss[k] = -INFINITY; si[k] = 0x40000000 + k; }
    }
    __syncthreads();
    bitonicShared(ss, si, 2048);
    for (int k = threadIdx.x; k < KC; k += SORTT) {
        int sl = si[k];                 // all 1500 real entries sort before pads
        int src = b * KC + sl;
        int dst = b * KC + k;
        float sc = ss[k];
        int lab = clb[src];
        ssc[dst] = sc; slb[dst] = lab;
        float off = __fmul_rn((float)lab, 1025.0f);   // offset = max(800,1024)+1
        #pragma unroll
        for (int q = 0; q < 4; ++q) {
            float v = cbox[src * 4 + q];
            sbox[dst * 4 + q] = v;
            obox[dst * 4 + q] = __fadd_rn(v, off);
        }
    }
}

// ---------------- K5b: suppression bitmask (iou > 0.6 && j > i) ----------------
// Writes COLUMN-MAJOR: MT[b][w][row]  (coalesced store; coalesced column loads in k_nms)
__global__ __launch_bounds__(64) void k_iou(const float* __restrict__ obox,
                                            unsigned long long* __restrict__ MT) {
    int w = blockIdx.x, tile = blockIdx.y, b = blockIdx.z;
    if (w < tile) return;
    int lane = threadIdx.x;
    __shared__ float4 sj[64];
    __shared__ float aj[64];
    const float4* op = (const float4*)obox + (size_t)b * KC;
    int j0 = w * 64;
    int jl = j0 + lane;
    float4 vj = op[(jl < KC) ? jl : (KC - 1)];
    sj[lane] = vj;
    aj[lane] = __fmul_rn(__fsub_rn(vj.z, vj.x), __fsub_rn(vj.w, vj.y));
    int i = tile * 64 + lane;
    float4 bi = op[(i < KC) ? i : (KC - 1)];
    float ai = __fmul_rn(__fsub_rn(bi.z, bi.x), __fsub_rn(bi.w, bi.y));
    __syncthreads();
    unsigned long long bits = 0;
    int jmax = min(64, KC - j0);
    for (int jj = 0; jj < jmax; ++jj) {
        float4 bj = sj[jj];            // wave-uniform -> LDS broadcast
        float xx1 = fmaxf(bi.x, bj.x), yy1 = fmaxf(bi.y, bj.y);
        float xx2 = fminf(bi.z, bj.z), yy2 = fminf(bi.w, bj.w);
        float ww = fmaxf(__fsub_rn(xx2, xx1), 0.0f);
        float hh = fmaxf(__fsub_rn(yy2, yy1), 0.0f);
        float inter = __fmul_rn(ww, hh);
        float uni = __fsub_rn(__fadd_rn(ai, aj[jj]), inter);
        float iou = __fdiv_rn(inter, fmaxf(uni, 1e-9f));
        bool kp = ((j0 + jj) > i) && (iou > 0.6f);
        bits |= kp ? (1ull << jj) : 0ull;
    }
    if (i >= KC) bits = 0;
    MT[((size_t)b * WORDS + w) * KROWS + i] = bits;
}

// ---------------- K5c: multi-wave LDS-pipelined greedy scan ----------------
// 4 waves/image: waves 1-3 stream column t+2 into a 3-deep LDS ring (coalesced,
// guaranteed MLP, no VGPR arrays for the register allocator to serialize);
// wave 0 computes tile t from LDS (pipelined ds_reads + butterfly + sparse greedy).
__global__ __launch_bounds__(NMST) void k_nms(
        const unsigned long long* __restrict__ MT, const float* __restrict__ ssc,
        const int* __restrict__ slb, const float* __restrict__ sbox, float* __restrict__ out) {
    int b = blockIdx.x, tid = threadIdx.x, wave = tid >> 6, lane = tid & 63;
    __shared__ unsigned long long colbuf[3][KROWS];   // 3 x 12 KB
    __shared__ unsigned long long keptS[WORDS];
    __shared__ unsigned long long validS[WORDS];

    // zero-fill this image's output slices (d_out is poisoned before every launch)
    for (int k = tid; k < POSTN * 5; k += NMST) out[(size_t)b * POSTN * 5 + k] = 0.0f;
    for (int k = tid; k < POSTN; k += NMST) {
        out[(size_t)NB * POSTN * 5 + b * POSTN + k] = 0.0f;                 // labels
        out[(size_t)NB * POSTN * 5 + NB * POSTN + b * POSTN + k] = 0.0f;    // valid
    }
    if (tid < WORDS) keptS[tid] = 0;
    const float* sp = ssc + b * KC;
    for (int c = wave; c < WORDS; c += 4) {
        int i = c * 64 + lane;
        bool f = (i < KC) && (sp[i] > 0.0f);
        unsigned long long m = __ballot(f);
        if (lane == 0) validS[c] = m;
    }
    const unsigned long long* Mb = MT + (size_t)b * WORDS * KROWS;
    // prologue: waves 1-3 load columns 0 and 1
    if (wave > 0) {
        int lt = tid - 64;   // 0..191
        for (int k = lt; k < KROWS; k += 192) colbuf[0][k] = Mb[k];
        for (int k = lt; k < KROWS; k += 192) colbuf[1][k] = Mb[KROWS + k];
    }
    __syncthreads();

    for (int t = 0; t < WORDS; ++t) {
        if (wave > 0 && t + 2 < WORDS) {       // prefetch column t+2
            int lt = tid - 64;
            const unsigned long long* cp = Mb + (size_t)(t + 2) * KROWS;
            unsigned long long* dst = colbuf[(t + 2) % 3];
            for (int k = lt; k < KROWS; k += 192) dst[k] = cp[k];
        }
        if (wave == 0) {
            const unsigned long long* cur = colbuf[t % 3];
            unsigned long long D = cur[t * 64 + lane];
            unsigned long long acc = 0;
            #pragma unroll
            for (int c = 0; c < WORDS; ++c) {   // always-issued pipelined ds_reads, masked OR
                unsigned long long v = cur[c * 64 + lane];
                unsigned long long kc = keptS[c];
                bool use = (c < t) && ((kc >> lane) & 1ull);
                acc |= use ? v : 0ull;
            }
            #pragma unroll
            for (int s = 1; s < 64; s <<= 1) acc |= __shfl_xor(acc, s, 64);

            unsigned long long validT = validS[t];
            unsigned long long rem = acc;
            unsigned long long sup = __ballot(D != 0ull) & validT;
            unsigned long long todoS = sup;
            while (todoS) {
                int r = __builtin_ctzll(todoS);
                todoS &= todoS - 1;
                if (!((rem >> r) & 1ull)) {
                    unsigned long long Dr = readlane64(D, r);
                    rem |= Dr;
                    todoS &= ~Dr;
                }
            }
            if (lane == 0) keptS[t] = validT & ~rem;
        }
        __syncthreads();
    }

    // emit first 100 kept in score order (wave 0)
    if (wave == 0) {
        unsigned long long mybit = 1ull << lane;
        int base = 0;
        for (int c = 0; c < WORDS && base < POSTN; ++c) {
            unsigned long long kw = keptS[c];
            bool f = (kw & mybit) != 0ull;
            int rank = base + __popcll(kw & (mybit - 1ull));
            if (f && rank < POSTN) {
                int i = c * 64 + lane;
                int src = b * KC + i;
                float* o5 = out + ((size_t)b * POSTN + rank) * 5;
                o5[0] = sbox[src * 4 + 0]; o5[1] = sbox[src * 4 + 1];
                o5[2] = sbox[src * 4 + 2]; o5[3] = sbox[src * 4 + 3];
                o5[4] = ssc[src];
                out[(size_t)NB * POSTN * 5 + b * POSTN + rank] = (float)slb[src];
                out[(size_t)NB * POSTN * 5 + NB * POSTN + b * POSTN + rank] = 1.0f;
            }
            base += __popcll(kw);
        }
    }
}

// ---------------- launch ----------------
extern "C" void kernel_launch(void* const* d_in, const int* in_sizes, int n_in,
                              void* d_out, int out_size, void* d_ws, size_t ws_size,
                              hipStream_t stream) {
    const float *loc[5], *cls[5], *box[5], *ctr[5];
    for (int l = 0; l < 5; ++l) {
        loc[l] = (const float*)d_in[l * 4 + 0];
        cls[l] = (const float*)d_in[l * 4 + 1];
        box[l] = (const float*)d_in[l * 4 + 2];
        ctr[l] = (const float*)d_in[l * 4 + 3];
    }
    char* ws = (char*)d_ws;
    unsigned* hist = (unsigned*)(ws + OFF_HIST);
    unsigned* cnt  = (unsigned*)(ws + OFF_CNT);
    Cand* cand     = (Cand*)(ws + OFF_CAND);
    float* cbox    = (float*)(ws + OFF_CBOX);
    float* csc     = (float*)(ws + OFF_CSC);
    int*   clb     = (int*)(ws + OFF_CLB);
    float* ssc     = (float*)(ws + OFF_SSC);
    int*   slb     = (int*)(ws + OFF_SLB);
    float* sbox    = (float*)(ws + OFF_SBOX);
    float* obox    = (float*)(ws + OFF_OBOX);
    unsigned long long* MT = (unsigned long long*)(ws + OFF_M);
    float* sct     = (float*)(ws + OFF_SCT);
    unsigned short* gmx = (unsigned short*)(ws + OFF_GMX);
    float* out = (float*)d_out;

    int zn = (int)(OFF_CAND / 4);
    int initBlocks = (max(zn, SCTN) + THREADS - 1) / THREADS;
    k_init<<<initBlocks, THREADS, 0, stream>>>(
        ctr[0], ctr[1], ctr[2], ctr[3], ctr[4], sct, (unsigned*)ws, zn);
    k_hist<<<dim3(CHUNKS, NB), THREADS, 0, stream>>>(
        cls[0], cls[1], cls[2], cls[3], cls[4], sct, gmx, hist);
    k_collect<<<dim3(CHUNKS, NB), THREADS, 0, stream>>>(
        cls[0], cls[1], cls[2], cls[3], cls[4], sct, gmx, hist, cand, cnt);
    k_select<<<NPAIR, THREADS, 0, stream>>>(
        cand, cnt,
        loc[0], loc[1], loc[2], loc[3], loc[4],
        box[0], box[1], box[2], box[3], box[4],
        cbox, csc, clb);
    k_sortimg<<<NB, SORTT, 0, stream>>>(csc, clb, cbox, ssc, slb, sbox, obox);
    k_iou<<<dim3(WORDS, WORDS, NB), 64, 0, stream>>>(obox, MT);
    k_nms<<<NB, NMST, 0, stream>>>(MT, ssc, slb, sbox, out);
}

// Round 10
// 315.871 us; speedup vs baseline: 1.1116x; 1.1116x over previous
//
#include <hip/hip_runtime.h>
#include <math.h>

#define THREADS 256
#define SORTT 1024

// ---------------- problem constants (fixed by reference setup) ----------------
constexpr int NLEV  = 5;
constexpr int NB    = 16;     // batch
constexpr int NC    = 80;     // classes (label = c+1)
constexpr int TOPN  = 300;
constexpr int KC    = NLEV * TOPN;   // 1500 candidates per image
constexpr int KROWS = 1536;          // padded rows for NMS bitmask
constexpr int WORDS = 24;            // 1536 / 64
constexpr int POSTN = 100;
constexpr int CAP   = 4096;          // per-(b,level) candidate pool
constexpr int NBINS = 2048;          // score-histogram bins over [0.25, 1.0)
constexpr int NPAIR = NLEV * NB;     // 80

constexpr int HW0 = 12800, HW1 = 3200, HW2 = 800, HW3 = 208, HW4 = 56;
constexpr int CH0 = 63, CH1 = 16, CH2 = 4, CH3 = 2, CH4 = 1;  // 16384-elem chunks per (b,level)
constexpr int CHUNKS = CH0 + CH1 + CH2 + CH3 + CH4;           // 86
constexpr int CHUNK_ELEMS = 16384;

// sigmoid(ctr) precompute: per-level bases into sct[] (floats), layout [li][b][hw]
constexpr int SCTB0 = 0;
constexpr int SCTB1 = 204800;
constexpr int SCTB2 = 256000;
constexpr int SCTB3 = 268800;
constexpr int SCTB4 = 272128;
constexpr int SCTN  = 273024;

// group-max skip list: 256-element groups, layout [li][b][g] (u16)
constexpr int GPL0 = 4000, GPL1 = 1000, GPL2 = 250, GPL3 = 65, GPL4 = 18;
constexpr int GMXB0 = 0;
constexpr int GMXB1 = GMXB0 + NB * GPL0;
constexpr int GMXB2 = GMXB1 + NB * GPL1;
constexpr int GMXB3 = GMXB2 + NB * GPL2;
constexpr int GMXB4 = GMXB3 + NB * GPL3;
constexpr int GMXN  = GMXB4 + NB * GPL4;

// ---------------- workspace layout ----------------
constexpr size_t align256(size_t x) { return (x + 255) & ~(size_t)255; }
constexpr size_t OFF_HIST = 0;
constexpr size_t OFF_CNT  = OFF_HIST + (size_t)NPAIR * NBINS * 4;
constexpr size_t OFF_CAND = align256(OFF_CNT + (size_t)NPAIR * 4);
constexpr size_t OFF_CBOX = align256(OFF_CAND + (size_t)NPAIR * CAP * 8);
constexpr size_t OFF_CSC  = align256(OFF_CBOX + (size_t)NB * KC * 4 * 4);
constexpr size_t OFF_CLB  = align256(OFF_CSC  + (size_t)NB * KC * 4);
constexpr size_t OFF_SSC  = align256(OFF_CLB  + (size_t)NB * KC * 4);
constexpr size_t OFF_SLB  = align256(OFF_SSC  + (size_t)NB * KC * 4);
constexpr size_t OFF_SBOX = align256(OFF_SLB  + (size_t)NB * KC * 4);
constexpr size_t OFF_OBOX = align256(OFF_SBOX + (size_t)NB * KC * 4 * 4);
constexpr size_t OFF_M    = align256(OFF_OBOX + (size_t)NB * KC * 4 * 4);
constexpr size_t OFF_SCT  = align256(OFF_M + (size_t)NB * KROWS * WORDS * 8);
constexpr size_t OFF_GMX  = align256(OFF_SCT + (size_t)SCTN * 4);
// total ~15.8 MB

struct Cand { float s; int i; };
typedef unsigned long long u64;

// ---------------- helpers ----------------
__device__ __forceinline__ float sigm(float x) { return 1.0f / (1.0f + expf(-x)); }

// fast sigmoid (hw v_exp_f32 + v_rcp_f32, <=~4 ulp). Used ONLY for the histogram /
// skip-list (threshold selection): |approx key - exact key| <= 1 bin, compensated
// by collecting key >= TA-1 and gating groups by gmx+1 >= Tv. Collect/select use
// the exact sigm() so the final output is bit-identical.
__device__ __forceinline__ float sigf(float x) {
#if __has_builtin(__builtin_amdgcn_exp2f) && __has_builtin(__builtin_amdgcn_rcpf)
    float e = __builtin_amdgcn_exp2f(__fmul_rn(x, -1.44269504088896340736f));
    return __builtin_amdgcn_rcpf(__fadd_rn(1.0f, e));
#else
    return 1.0f / (1.0f + __expf(-x));
#endif
}

// monotone key over score in (0,1): 2048 bins over [0.25,1.0), everything below -> bin 0
__device__ __forceinline__ unsigned scoreKey(float s) {
    unsigned b = __float_as_uint(s);
    unsigned k = (b < 0x3E800000u) ? 0u : ((b - 0x3E800000u) >> 13);
    return (k > 2047u) ? 2047u : k;
}

__device__ __forceinline__ u64 readlane64(u64 v, int l) {
    unsigned lo = (unsigned)__builtin_amdgcn_readlane((int)(unsigned)(v & 0xffffffffull), l);
    unsigned hi = (unsigned)__builtin_amdgcn_readlane((int)(unsigned)(v >> 32), l);
    return ((u64)hi << 32) | lo;
}

// async global->LDS DMA, 16B/lane: lane l loads g + l*16B, deposits at lds + l*16B.
// No VGPR round-trip, no per-element waitcnt -> a whole column's loads stay in flight.
__device__ __forceinline__ void gload_lds16(const u64* g, u64* lds) {
    __builtin_amdgcn_global_load_lds(
        (const __attribute__((address_space(1))) void*)g,
        (__attribute__((address_space(3))) void*)lds, 16, 0, 0);
}

__device__ void bitonicShared(float* ss, int* si, int N) {
    for (int k = 2; k <= N; k <<= 1) {
        for (int j = k >> 1; j > 0; j >>= 1) {
            __syncthreads();
            for (int i = threadIdx.x; i < N; i += blockDim.x) {
                int ixj = i ^ j;
                if (ixj > i) {
                    float s1 = ss[i], s2 = ss[ixj];
                    int a1 = si[i], a2 = si[ixj];
                    bool bef = (s1 > s2) || (s1 == s2 && a1 < a2);   // desc, idx asc
                    bool up = ((i & k) == 0);
                    if (up ? !bef : bef) { ss[i] = s2; ss[ixj] = s1; si[i] = a2; si[ixj] = a1; }
                }
            }
        }
    }
    __syncthreads();
}

// ---------------- K0: fused zero (hist+cnt) + sigmoid(ctr) precompute ----------------
__global__ __launch_bounds__(THREADS) void k_init(
        const float* t0, const float* t1, const float* t2, const float* t3, const float* t4,
        float* __restrict__ sct, unsigned* __restrict__ zp, int zn) {
    int i = blockIdx.x * THREADS + threadIdx.x;
    if (i < zn) zp[i] = 0;
    if (i < SCTN) {
        float x;
        if (i < SCTB1)      x = t0[i - SCTB0];
        else if (i < SCTB2) x = t1[i - SCTB1];
        else if (i < SCTB3) x = t2[i - SCTB2];
        else if (i < SCTB4) x = t3[i - SCTB3];
        else                x = t4[i - SCTB4];
        sct[i] = sigm(x);   // exact: same formula as reference sigmoid usage
    }
}

// ---------------- K1: approx histogram + per-256-group max approx key ----------------
// 512-elem blocks: each lane loads 2x float4 (32B contiguous). All NE and HW are
// divisible by 8, so the two float4s never straddle a class row.
template<int HW, int SCTB, int GPL, int GMXB>
__device__ __forceinline__ void histChunkV(int chunkLocal, int b,
        const float* __restrict__ cls, const float* __restrict__ sct,
        unsigned short* __restrict__ gmx, unsigned* __restrict__ h) {
    constexpr int NE = HW * NC;
    const float* cp = cls + (size_t)b * NE;
    const float* tb = sct + SCTB + b * HW;
    unsigned short* gp = gmx + GMXB + (size_t)b * GPL;
    int w = threadIdx.x >> 6, lane = threadIdx.x & 63;
    int half = lane >> 5, hlane = lane & 31;
    for (int bi = w; bi < 32; bi += 4) {
        int ebase = (chunkLocal * 32 + bi) * 512;
        if (ebase >= NE) break;
        int e = ebase + lane * 8;
        int kmax = 0;
        if (e < NE) {   // NE%8==0 -> e<NE implies e+7<NE
            int c = e / HW; int hwb = e - c * HW;
            float4 xa = *(const float4*)(cp + e);
            float4 xb = *(const float4*)(cp + e + 4);
            float4 ta = *(const float4*)(tb + hwb);
            float4 tc = *(const float4*)(tb + hwb + 4);
            float xs[8] = {xa.x, xa.y, xa.z, xa.w, xb.x, xb.y, xb.z, xb.w};
            float ts[8] = {ta.x, ta.y, ta.z, ta.w, tc.x, tc.y, tc.z, tc.w};
            #pragma unroll
            for (int q = 0; q < 8; ++q) {
                float scls = sigf(xs[q]);                // FAST sigmoid (approx key)
                float s = __fmul_rn(scls, ts[q]);
                unsigned key = scoreKey(s);
                if (key) atomicAdd(&h[key], 1u);
                kmax = max(kmax, (int)key);
            }
        }
        // half-wave (32-lane) max reduce: each half covers one 256-elem group
        #pragma unroll
        for (int sh = 1; sh < 32; sh <<= 1) kmax = max(kmax, __shfl_xor(kmax, sh, 64));
        int g = (ebase >> 8) + half;
        if (hlane == 0 && g * 256 < NE) gp[g] = (unsigned short)kmax;
    }
}

__global__ __launch_bounds__(THREADS) void k_hist(
        const float* c0, const float* c1, const float* c2, const float* c3, const float* c4,
        const float* __restrict__ sct, unsigned short* __restrict__ gmx, unsigned* ghist) {
    __shared__ unsigned h[NBINS];
    for (int k = threadIdx.x; k < NBINS; k += THREADS) h[k] = 0;
    __syncthreads();
    int cx = blockIdx.x, b = blockIdx.y;
    int li;
    if (cx < CH0)                 { histChunkV<HW0,SCTB0,GPL0,GMXB0>(cx, b, c0, sct, gmx, h); li = 0; }
    else if (cx < CH0+CH1)        { histChunkV<HW1,SCTB1,GPL1,GMXB1>(cx-CH0, b, c1, sct, gmx, h); li = 1; }
    else if (cx < CH0+CH1+CH2)    { histChunkV<HW2,SCTB2,GPL2,GMXB2>(cx-CH0-CH1, b, c2, sct, gmx, h); li = 2; }
    else if (cx < CH0+CH1+CH2+CH3){ histChunkV<HW3,SCTB3,GPL3,GMXB3>(cx-CH0-CH1-CH2, b, c3, sct, gmx, h); li = 3; }
    else                          { histChunkV<HW4,SCTB4,GPL4,GMXB4>(cx-CH0-CH1-CH2-CH3, b, c4, sct, gmx, h); li = 4; }
    __syncthreads();
    unsigned* gp = ghist + (size_t)(li * NB + b) * NBINS;
    for (int k = threadIdx.x; k < NBINS; k += THREADS) {
        unsigned v = h[k];
        if (v) atomicAdd(&gp[k], v);
    }
}

// ---------------- K3: skip-list compaction, batched loads; inline threshold ----------------
constexpr int LBUF = 1024;
constexpr int GB = 8;

template<int HW, int SCTB, int GPL, int GMXB>
__device__ __forceinline__ void collectChunkV(int chunkLocal, int b, int li, unsigned Tv,
        const float* __restrict__ cls, const float* __restrict__ sct,
        const unsigned short* __restrict__ gmx,
        Cand* __restrict__ candAll, unsigned* __restrict__ cnt,
        Cand* __restrict__ lbuf, unsigned* __restrict__ lcnt,
        short* __restrict__ glist, int* __restrict__ gcnt) {
    constexpr int NE = HW * NC;
    int pid = li * NB + b;
    Cand* cd = candAll + (size_t)pid * CAP;
    const float* cp = cls + (size_t)b * NE;
    const float* tb = sct + SCTB + b * HW;
    const unsigned short* gp = gmx + GMXB + (size_t)b * GPL;
    // build compact passing-group list
    if (threadIdx.x < 64) {
        int g = chunkLocal * 64 + threadIdx.x;
        bool ok = ((size_t)g * 256 < (size_t)NE);
        if (ok && Tv) ok = ((unsigned)gp[g] + 1u >= Tv);   // gmx is max APPROX key: +1 slack
        u64 m = __ballot(ok);
        int pos = __popcll(m & ((1ull << threadIdx.x) - 1ull));
        if (ok) glist[pos] = (short)g;
        if (threadIdx.x == 0) *gcnt = __popcll(m);
    }
    __syncthreads();
    int n = *gcnt;
    for (int base = 0; base < n; base += GB) {
        float xv[GB], tv[GB];
        int ev[GB];
        bool okv[GB];
        #pragma unroll
        for (int q = 0; q < GB; ++q) {
            int gi = base + q;
            int g = glist[(gi < n) ? gi : 0];
            int e = g * 256 + (int)threadIdx.x;
            bool ok = (gi < n) && (e < NE);
            e = ok ? e : 0;
            int c = e / HW; int hw = e - c * HW;
            xv[q] = cp[e];
            tv[q] = tb[hw];
            ev[q] = e;
            okv[q] = ok;
        }
        __builtin_amdgcn_sched_barrier(0);   // keep the 2*GB loads batched above the uses
        #pragma unroll
        for (int q = 0; q < GB; ++q) {
            float scls = sigm(xv[q]);        // EXACT sigmoid for stored score
            float s = __fmul_rn(scls, tv[q]);
            unsigned key = scoreKey(s);
            bool take = okv[q] && (Tv ? (key >= Tv) : (scls > 0.05f));
            if (take) {
                int e = ev[q];
                int c = e / HW; int hw = e - c * HW;
                unsigned slot = atomicAdd(lcnt, 1u);
                if (slot < (unsigned)LBUF) { lbuf[slot].s = s; lbuf[slot].i = hw * NC + c; }
                else {
                    unsigned gs = atomicAdd(&cnt[pid], 1u);   // rare fallback
                    if (gs < (unsigned)CAP) { cd[gs].s = s; cd[gs].i = hw * NC + c; }
                }
            }
        }
    }
}

__global__ __launch_bounds__(THREADS) void k_collect(
        const float* c0, const float* c1, const float* c2, const float* c3, const float* c4,
        const float* __restrict__ sct, const unsigned short* __restrict__ gmx,
        const unsigned* __restrict__ ghist, Cand* cand, unsigned* cnt) {
    __shared__ Cand lbuf[LBUF];
    __shared__ unsigned lcnt, gbase;
    __shared__ short glist[64];
    __shared__ int gcnt;
    __shared__ unsigned seg[THREADS];
    __shared__ unsigned shTv;
    if (threadIdx.x == 0) lcnt = 0;
    int cx = blockIdx.x, b = blockIdx.y;
    int li, cl;
    if (cx < CH0)                  { li = 0; cl = cx; }
    else if (cx < CH0+CH1)         { li = 1; cl = cx - CH0; }
    else if (cx < CH0+CH1+CH2)     { li = 2; cl = cx - CH0 - CH1; }
    else if (cx < CH0+CH1+CH2+CH3) { li = 3; cl = cx - CH0 - CH1 - CH2; }
    else                           { li = 4; cl = cx - CH0 - CH1 - CH2 - CH3; }
    int pid = li * NB + b;
    // inline threshold (same math as the old k_thresh, recomputed per block)
    {
        const unsigned* h = ghist + (size_t)pid * NBINS;
        constexpr int SB = NBINS / THREADS;   // 8
        unsigned s = 0;
        for (int k = 0; k < SB; ++k) s += h[threadIdx.x * SB + k];
        seg[threadIdx.x] = s;
        __syncthreads();
        if (threadIdx.x == 0) {
            unsigned acc = 0; unsigned TA = 0;
            int t = THREADS - 1;
            for (; t >= 0; --t) {
                if (acc + seg[t] >= (unsigned)TOPN) break;
                acc += seg[t];
            }
            if (t >= 0) {
                int lo = t * SB;
                int bin = lo + SB - 1;
                for (; bin >= lo; --bin) { acc += h[bin]; if (acc >= (unsigned)TOPN) break; }
                TA = (unsigned)max(bin, lo);
            }
            shTv = (TA >= 1) ? (TA - 1) : 0;   // 0 => degenerate fallback (collect scls>0.05)
        }
        __syncthreads();
    }
    unsigned Tv = shTv;
    switch (li) {
        case 0: collectChunkV<HW0,SCTB0,GPL0,GMXB0>(cl, b, 0, Tv, c0, sct, gmx, cand, cnt, lbuf, &lcnt, glist, &gcnt); break;
        case 1: collectChunkV<HW1,SCTB1,GPL1,GMXB1>(cl, b, 1, Tv, c1, sct, gmx, cand, cnt, lbuf, &lcnt, glist, &gcnt); break;
        case 2: collectChunkV<HW2,SCTB2,GPL2,GMXB2>(cl, b, 2, Tv, c2, sct, gmx, cand, cnt, lbuf, &lcnt, glist, &gcnt); break;
        case 3: collectChunkV<HW3,SCTB3,GPL3,GMXB3>(cl, b, 3, Tv, c3, sct, gmx, cand, cnt, lbuf, &lcnt, glist, &gcnt); break;
        default: collectChunkV<HW4,SCTB4,GPL4,GMXB4>(cl, b, 4, Tv, c4, sct, gmx, cand, cnt, lbuf, &lcnt, glist, &gcnt); break;
    }
    __syncthreads();
    unsigned n = lcnt; if (n > (unsigned)LBUF) n = LBUF;
    if (threadIdx.x == 0) gbase = n ? atomicAdd(&cnt[pid], n) : 0u;
    __syncthreads();
    Cand* cd = cand + (size_t)pid * CAP;
    for (unsigned i = threadIdx.x; i < n; i += THREADS) {
        unsigned s = gbase + i;
        if (s < (unsigned)CAP) cd[s] = lbuf[i];
    }
}

// ---------------- K4: exact top-300 per (b,level) + decode ----------------
__global__ __launch_bounds__(THREADS) void k_select(
        const Cand* __restrict__ candAll, const unsigned* __restrict__ cntAll,
        const float* l0, const float* l1, const float* l2, const float* l3, const float* l4,
        const float* b0, const float* b1, const float* b2, const float* b3, const float* b4,
        float* __restrict__ cbox, float* __restrict__ csc, int* __restrict__ clb) {
    __shared__ float ss[CAP];
    __shared__ int si[CAP];
    int pid = blockIdx.x;
    int li = pid / NB, b = pid - li * NB;
    int n = (int)min(cntAll[pid], (unsigned)CAP);
    const Cand* cd = candAll + (size_t)pid * CAP;
    int N = 2; while (N < n) N <<= 1;
    for (int k = threadIdx.x; k < N; k += THREADS) {
        if (k < n) { ss[k] = cd[k].s; si[k] = cd[k].i; }
        else       { ss[k] = -INFINITY; si[k] = 0x40000000 + k; }
    }
    __syncthreads();
    bitonicShared(ss, si, N);

    const float* locp; const float* boxp; int HW;
    switch (li) {
        case 0: locp = l0; boxp = b0; HW = HW0; break;
        case 1: locp = l1; boxp = b1; HW = HW1; break;
        case 2: locp = l2; boxp = b2; HW = HW2; break;
        case 3: locp = l3; boxp = b3; HW = HW3; break;
        default: locp = l4; boxp = b4; HW = HW4; break;
    }
    for (int j = threadIdx.x; j < TOPN; j += THREADS) {
        int cidx = b * KC + li * TOPN + j;
        bool ok = (j < n);
        float s = ok ? ss[j] : -INFINITY;
        ok = ok && (s > 0.0f);
        if (ok) {
            int idx = si[j];
            int hw = idx / NC, c = idx - hw * NC;
            float lx = locp[hw * 2 + 0], ly = locp[hw * 2 + 1];
            const float* bp = boxp + (size_t)b * 4 * HW + hw;
            float bl = bp[0], bt = bp[HW], br = bp[2 * HW], bb = bp[3 * HW];
            float x1 = fminf(fmaxf(__fsub_rn(lx, bl), 0.0f), 1023.0f);
            float y1 = fminf(fmaxf(__fsub_rn(ly, bt), 0.0f),  799.0f);
            float x2 = fminf(fmaxf(__fadd_rn(lx, br), 0.0f), 1023.0f);
            float y2 = fminf(fmaxf(__fadd_rn(ly, bb), 0.0f),  799.0f);
            cbox[cidx * 4 + 0] = x1; cbox[cidx * 4 + 1] = y1;
            cbox[cidx * 4 + 2] = x2; cbox[cidx * 4 + 3] = y2;
            csc[cidx] = sqrtf(fmaxf(s, 1e-12f));
            clb[cidx] = c + 1;
        } else {
            cbox[cidx * 4 + 0] = 0.0f; cbox[cidx * 4 + 1] = 0.0f;
            cbox[cidx * 4 + 2] = 0.0f; cbox[cidx * 4 + 3] = 0.0f;
            csc[cidx] = -INFINITY;
            clb[cidx] = 0;
        }
    }
}

// ---------------- K5a: per-image sort by score desc (1024 threads) ----------------
__global__ __launch_bounds__(SORTT) void k_sortimg(
        const float* __restrict__ csc, const int* __restrict__ clb, const float* __restrict__ cbox,
        float* __restrict__ ssc, int* __restrict__ slb, float* __restrict__ sbox, float* __restrict__ obox) {
    int b = blockIdx.x;
    __shared__ float ss[2048];
    __shared__ int si[2048];
    for (int k = threadIdx.x; k < 2048; k += SORTT) {
        if (k < KC) { ss[k] = csc[b * KC + k]; si[k] = k; }
        else        { ss[k] = -INFINITY; si[k] = 0x40000000 + k; }
    }
    __syncthreads();
    bitonicShared(ss, si, 2048);
    for (int k = threadIdx.x; k < KC; k += SORTT) {
        int sl = si[k];                 // all 1500 real entries sort before pads
        int src = b * KC + sl;
        int dst = b * KC + k;
        float sc = ss[k];
        int lab = clb[src];
        ssc[dst] = sc; slb[dst] = lab;
        float off = __fmul_rn((float)lab, 1025.0f);   // offset = max(800,1024)+1
        #pragma unroll
        for (int q = 0; q < 4; ++q) {
            float v = cbox[src * 4 + q];
            sbox[dst * 4 + q] = v;
            obox[dst * 4 + q] = __fadd_rn(v, off);
        }
    }
}

// ---------------- K5b: suppression bitmask (iou > 0.6 && j > i) ----------------
// Writes COLUMN-MAJOR: MT[b][w][row]  (coalesced store; coalesced column loads in k_nms)
__global__ __launch_bounds__(64) void k_iou(const float* __restrict__ obox,
                                            u64* __restrict__ MT) {
    int w = blockIdx.x, tile = blockIdx.y, b = blockIdx.z;
    if (w < tile) return;
    int lane = threadIdx.x;
    __shared__ float4 sj[64];
    __shared__ float aj[64];
    const float4* op = (const float4*)obox + (size_t)b * KC;
    int j0 = w * 64;
    int jl = j0 + lane;
    float4 vj = op[(jl < KC) ? jl : (KC - 1)];
    sj[lane] = vj;
    aj[lane] = __fmul_rn(__fsub_rn(vj.z, vj.x), __fsub_rn(vj.w, vj.y));
    int i = tile * 64 + lane;
    float4 bi = op[(i < KC) ? i : (KC - 1)];
    float ai = __fmul_rn(__fsub_rn(bi.z, bi.x), __fsub_rn(bi.w, bi.y));
    __syncthreads();
    u64 bits = 0;
    int jmax = min(64, KC - j0);
    for (int jj = 0; jj < jmax; ++jj) {
        float4 bj = sj[jj];            // wave-uniform -> LDS broadcast
        float xx1 = fmaxf(bi.x, bj.x), yy1 = fmaxf(bi.y, bj.y);
        float xx2 = fminf(bi.z, bj.z), yy2 = fminf(bi.w, bj.w);
        float ww = fmaxf(__fsub_rn(xx2, xx1), 0.0f);
        float hh = fmaxf(__fsub_rn(yy2, yy1), 0.0f);
        float inter = __fmul_rn(ww, hh);
        float uni = __fsub_rn(__fadd_rn(ai, aj[jj]), inter);
        float iou = __fdiv_rn(inter, fmaxf(uni, 1e-9f));
        bool kp = ((j0 + jj) > i) && (iou > 0.6f);
        bits |= kp ? (1ull << jj) : 0ull;
    }
    if (i >= KC) bits = 0;
    MT[((size_t)b * WORDS + w) * KROWS + i] = bits;
}

// ---------------- K5c: single-wave greedy scan, global_load_lds column DMA ----------------
// Column t+1 is DMA'd into a 2-deep LDS ring with global_load_lds (all loads in
// flight at once -> one memory latency per tile; no VGPR arrays to be sunk).
// Triangular: column t only needs rows < 64(t+1) (chunks c<=t, the written triangle).
__global__ __launch_bounds__(64) void k_nms(
        const u64* __restrict__ MT, const float* __restrict__ ssc,
        const int* __restrict__ slb, const float* __restrict__ sbox, float* __restrict__ out) {
    int b = blockIdx.x, lane = threadIdx.x;
    __shared__ u64 colbuf[2][KROWS];   // 2 x 12 KB ring

    // zero-fill this image's output slices (d_out is poisoned before every launch)
    for (int k = lane; k < POSTN * 5; k += 64) out[(size_t)b * POSTN * 5 + k] = 0.0f;
    for (int k = lane; k < POSTN; k += 64) {
        out[(size_t)NB * POSTN * 5 + b * POSTN + k] = 0.0f;                 // labels
        out[(size_t)NB * POSTN * 5 + NB * POSTN + b * POSTN + k] = 0.0f;    // valid
    }
    const float* sp = ssc + b * KC;
    u64 validV = 0;
    for (int c = 0; c < WORDS; ++c) {
        int i = c * 64 + lane;
        bool f = (i < KC) && (sp[i] > 0.0f);
        u64 m = __ballot(f);
        validV = (lane == c) ? m : validV;
    }
    u64 mybit = 1ull << lane;
    u64 keptV = 0;
    const u64* Mb = MT + (size_t)b * WORDS * KROWS;

    // prologue: column 0 (needs rows 0..63; one 1KB DMA covers rows 0..127)
    gload_lds16(Mb + lane * 2, &colbuf[0][0]);
    __syncthreads();   // drain -> col 0 ready

    for (int t = 0; t < WORDS; ++t) {
        // issue column t+1 DMA (rows < 64(t+2)), all instructions back-to-back
        if (t + 1 < WORDS) {
            const u64* src = Mb + (size_t)(t + 1) * KROWS;
            u64* dst = &colbuf[(t + 1) & 1][0];
            int nins = (min(64 * (t + 2), KROWS) + 127) >> 7;   // 128 u64 (1 KB) per DMA
            for (int i = 0; i < nins; ++i)
                gload_lds16(src + i * 128 + lane * 2, dst + i * 128);
        }

        // compute tile t from colbuf[t&1] (ready since previous barrier)
        const u64* cur = &colbuf[t & 1][0];
        u64 D = cur[t * 64 + lane];
        u64 acc = 0;
        #pragma unroll
        for (int c = 0; c < WORDS; ++c) {     // pipelined ds_reads, masked OR
            u64 v = cur[c * 64 + lane];
            u64 kc = readlane64(keptV, c);
            bool use = (c < t) && ((kc >> lane) & 1ull);
            acc |= use ? v : 0ull;
        }
        #pragma unroll
        for (int s = 1; s < 64; s <<= 1) acc |= __shfl_xor(acc, s, 64);

        u64 validT = readlane64(validV, t);
        u64 rem = acc;
        u64 sup = __ballot(D != 0ull) & validT;
        u64 todoS = sup;
        while (todoS) {
            int r = __builtin_ctzll(todoS);
            todoS &= todoS - 1;
            if (!((rem >> r) & 1ull)) {
                u64 Dr = readlane64(D, r);
                rem |= Dr;
                todoS &= ~Dr;
            }
        }
        u64 kept = validT & ~rem;
        keptV = (lane == t) ? kept : keptV;

        __syncthreads();   // drain column t+1's DMA before next tile reads it
    }

    // emit first 100 kept in score order
    int base = 0;
    for (int c = 0; c < WORDS && base < POSTN; ++c) {
        u64 kw = readlane64(keptV, c);
        bool f = (kw & mybit) != 0ull;
        int rank = base + __popcll(kw & (mybit - 1ull));
        if (f && rank < POSTN) {
            int i = c * 64 + lane;
            int src = b * KC + i;
            float* o5 = out + ((size_t)b * POSTN + rank) * 5;
            o5[0] = sbox[src * 4 + 0]; o5[1] = sbox[src * 4 + 1];
            o5[2] = sbox[src * 4 + 2]; o5[3] = sbox[src * 4 + 3];
            o5[4] = ssc[src];
            out[(size_t)NB * POSTN * 5 + b * POSTN + rank] = (float)slb[src];
            out[(size_t)NB * POSTN * 5 + NB * POSTN + b * POSTN + rank] = 1.0f;
        }
        base += __popcll(kw);
    }
}

// ---------------- launch ----------------
extern "C" void kernel_launch(void* const* d_in, const int* in_sizes, int n_in,
                              void* d_out, int out_size, void* d_ws, size_t ws_size,
                              hipStream_t stream) {
    const float *loc[5], *cls[5], *box[5], *ctr[5];
    for (int l = 0; l < 5; ++l) {
        loc[l] = (const float*)d_in[l * 4 + 0];
        cls[l] = (const float*)d_in[l * 4 + 1];
        box[l] = (const float*)d_in[l * 4 + 2];
        ctr[l] = (const float*)d_in[l * 4 + 3];
    }
    char* ws = (char*)d_ws;
    unsigned* hist = (unsigned*)(ws + OFF_HIST);
    unsigned* cnt  = (unsigned*)(ws + OFF_CNT);
    Cand* cand     = (Cand*)(ws + OFF_CAND);
    float* cbox    = (float*)(ws + OFF_CBOX);
    float* csc     = (float*)(ws + OFF_CSC);
    int*   clb     = (int*)(ws + OFF_CLB);
    float* ssc     = (float*)(ws + OFF_SSC);
    int*   slb     = (int*)(ws + OFF_SLB);
    float* sbox    = (float*)(ws + OFF_SBOX);
    float* obox    = (float*)(ws + OFF_OBOX);
    u64* MT        = (u64*)(ws + OFF_M);
    float* sct     = (float*)(ws + OFF_SCT);
    unsigned short* gmx = (unsigned short*)(ws + OFF_GMX);
    float* out = (float*)d_out;

    int zn = (int)(OFF_CAND / 4);
    int initBlocks = (max(zn, SCTN) + THREADS - 1) / THREADS;
    k_init<<<initBlocks, THREADS, 0, stream>>>(
        ctr[0], ctr[1], ctr[2], ctr[3], ctr[4], sct, (unsigned*)ws, zn);
    k_hist<<<dim3(CHUNKS, NB), THREADS, 0, stream>>>(
        cls[0], cls[1], cls[2], cls[3], cls[4], sct, gmx, hist);
    k_collect<<<dim3(CHUNKS, NB), THREADS, 0, stream>>>(
        cls[0], cls[1], cls[2], cls[3], cls[4], sct, gmx, hist, cand, cnt);
    k_select<<<NPAIR, THREADS, 0, stream>>>(
        cand, cnt,
        loc[0], loc[1], loc[2], loc[3], loc[4],
        box[0], box[1], box[2], box[3], box[4],
        cbox, csc, clb);
    k_sortimg<<<NB, SORTT, 0, stream>>>(csc, clb, cbox, ssc, slb, sbox, obox);
    k_iou<<<dim3(WORDS, WORDS, NB), 64, 0, stream>>>(obox, MT);
    k_nms<<<NB, 64, 0, stream>>>(MT, ssc, slb, sbox, out);
}